// Round 3
// baseline (318.313 us; speedup 1.0000x reference)
//
#include <hip/hip_runtime.h>
#include <math.h>

#define D  32
#define BN 16384
#define PP 16

typedef __bf16 bf16x8 __attribute__((ext_vector_type(8)));
typedef __bf16 bf16x4 __attribute__((ext_vector_type(4)));
typedef float  floatx4 __attribute__((ext_vector_type(4)));

#define K1 1.44269504088896341f      // log2(e)
#define K2 2.88539008177792681f      // 2*log2(e)

// LDS image: only the MFMA A-operands.
//   Wu  = Wih[:,0:32] bf16 [gate][stride 40]  (80 B rows)
//   Whh = bf16 [gate][stride 40]
// acc-init from tiny GLOBAL tables (64 KB total, L1/L2-hot):
//   T0[hop][k][g] = bias[g] + Wih[g][32:64]@ent[k]   (bias carried here)
//   TR[hop][j][g] =           Wih[g][0:32]@rel[j]    (no bias)
// step0: acc = T0[seed] + Wu@u ; steps>=1: acc = TR[j] + T0[k] + Whh@h.
// Row byte-offsets precomputed per (hop,fb,p) in pidx (int4, dense).
#define WU_OFF     0
#define WHH_OFF    10240
#define WIMG_BYTES 20480
#define H_OFF      20480
#define LDS_BYTES  (WIMG_BYTES + 4 * 1280)   // + H: 4 waves x 1 chain x 16 x 80B

__device__ __forceinline__ float sigf(float x) {
    float e = __builtin_amdgcn_exp2f(-x * K1);
    return __builtin_amdgcn_rcpf(1.0f + e);
}
__device__ __forceinline__ float logsigf(float x) {
    float ax = fabsf(x);
    float l = log1pf(__expf(-ax));
    return (x >= 0.0f) ? -l : x - l;
}
__device__ __forceinline__ bf16x8 loadu8(const float* __restrict__ p) {
    float4 a = ((const float4*)p)[0], b = ((const float4*)p)[1];
    bf16x8 r = { (__bf16)a.x, (__bf16)a.y, (__bf16)a.z, (__bf16)a.w,
                 (__bf16)b.x, (__bf16)b.y, (__bf16)b.z, (__bf16)b.w };
    return r;
}

// ---------------------------------------------------------------------------
// ids 0..16383        : weight images (bf16, Wu/Whh per hop)
// ids 16384..24575    : T0 (2 hops x 32 k x 128 g, f32, bias included)
// ids 24576..32767    : TR (2 hops x 32 j x 128 g, f32, no bias)
// ids 32768..557055   : pidx (2 hops x 16384 fb x 16 p packed byte-offsets)
// id  557056          : zero out[0] (loss accumulator)
__global__ __launch_bounds__(256)
void prep_tables(const float* __restrict__ ent, const float* __restrict__ rel,
                 const float* __restrict__ wih0, const float* __restrict__ whh0,
                 const float* __restrict__ bih0, const float* __restrict__ bhh0,
                 const float* __restrict__ wih1, const float* __restrict__ whh1,
                 const float* __restrict__ bih1, const float* __restrict__ bhh1,
                 const int* __restrict__ items,
                 const int* __restrict__ lp0, const int* __restrict__ lp1,
                 float* __restrict__ T0, float* __restrict__ TR,
                 float* __restrict__ wimg, int* __restrict__ pidx,
                 float* __restrict__ out)
{
    const int id = blockIdx.x * 256 + threadIdx.x;
    if (id < 16384) {                            // weight images
        const int hop  = id >> 13;
        const int rest = id & 8191;
        const int mat  = rest >> 12;             // 0 = Wu, 1 = Whh
        const int e    = rest & 4095;
        const int gate = e >> 5, d = e & 31;
        float v = mat ? (hop ? whh1 : whh0)[(size_t)gate * 32 + d]
                      : (hop ? wih1 : wih0)[(size_t)gate * 64 + d];
        __bf16* base = (__bf16*)((char*)wimg + hop * WIMG_BYTES + mat * 10240);
        base[gate * 40 + d] = (__bf16)v;
    } else if (id < 24576) {                     // T0 = bias + We@ent
        const int idb = id - 16384;
        const int hop = idb >> 12;
        const int k   = (idb >> 7) & 31;
        const int g   = idb & 127;
        const float* wih = hop ? wih1 : wih0;
        const float4* w4 = (const float4*)(wih + (size_t)g * 64 + 32);
        const float4* e4 = (const float4*)(ent + (size_t)k * 32);
        float a = hop ? bih1[g] + bhh1[g] : bih0[g] + bhh0[g];
        #pragma unroll
        for (int i = 0; i < 8; ++i) {
            float4 w = w4[i], x = e4[i];
            a = fmaf(w.x, x.x, a); a = fmaf(w.y, x.y, a);
            a = fmaf(w.z, x.z, a); a = fmaf(w.w, x.w, a);
        }
        T0[hop * 4096 + k * 128 + g] = a;
    } else if (id < 32768) {                     // TR = Wr@rel (no bias)
        const int idb = id - 24576;
        const int hop = idb >> 12;
        const int j   = (idb >> 7) & 31;
        const int g   = idb & 127;
        const float* wih = hop ? wih1 : wih0;
        const float4* w4 = (const float4*)(wih + (size_t)g * 64);
        const float4* r4 = (const float4*)(rel + (size_t)j * 32);
        float a = 0.0f;
        #pragma unroll
        for (int i = 0; i < 8; ++i) {
            float4 w = w4[i], x = r4[i];
            a = fmaf(w.x, x.x, a); a = fmaf(w.y, x.y, a);
            a = fmaf(w.z, x.z, a); a = fmaf(w.w, x.w, a);
        }
        TR[hop * 4096 + j * 128 + g] = a;
    } else if (id < 32768 + 524288) {            // pidx packing
        const int c   = id - 32768;
        const int hop = c >> 18;
        const int rem = c & 262143;
        const int fb  = rem >> 4;
        const int p   = rem & 15;
        const int item = items[fb];
        const int hb = hop << 14;                // (hop*32 rows)*512 B
        int w0, w1, w2 = 0;
        if (hop == 0) {
            const int* il = lp0 + ((size_t)item * PP + p) * 3;
            w0 = hb + (il[0] << 9);
            w1 = (hb + (il[1] << 9)) | ((hb + (il[2] << 9)) << 16);
        } else {
            const int* il = lp1 + ((size_t)item * PP + p) * 5;
            w0 = hb + (il[0] << 9);
            w1 = (hb + (il[1] << 9)) | ((hb + (il[2] << 9)) << 16);
            w2 = (hb + (il[3] << 9)) | ((hb + (il[4] << 9)) << 16);
        }
        int4 v = { w0, w1, w2, 0 };
        *(int4*)(pidx + ((size_t)(hop * BN + fb) * PP + p) * 4) = v;
    } else if (id == 32768 + 524288) {
        out[0] = 0.0f;                           // loss accumulator
    }
}

// nonlin in C-layout D[gate][pair] (verified R10): lane (q=lane>>4, p=lane&15),
// tile mt holds gates 16mt+4q+r of pair p -> unit quartets hf=0: 4q+r,
// hf=1: 16+4q+r. 4 exp2 + 2 rcp + 1 exp2 per unit.
template<bool FIRST, bool LAST>
__device__ __forceinline__ void nonlin(
    floatx4* __restrict__ acc, float* __restrict__ cst,
    float* __restrict__ hlo, float* __restrict__ hhi,
    char* __restrict__ Hw, int q, int bnl)
{
    #pragma unroll
    for (int hf = 0; hf < 2; ++hf) {
        float* hout = hf ? hhi : hlo;
        #pragma unroll
        for (int r = 0; r < 4; ++r) {
            float gi = acc[0 + hf][r], gf = acc[2 + hf][r],
                  gg = acc[4 + hf][r], go = acc[6 + hf][r];
            float Ai = 1.0f + __builtin_amdgcn_exp2f(-gi * K1);
            float Af = 1.0f + __builtin_amdgcn_exp2f(-gf * K1);
            float G2 = __builtin_amdgcn_exp2f(gg * K2);
            float Gp = G2 + 1.0f, Gm = G2 - 1.0f;
            float cold = FIRST ? 0.0f : cst[hf * 4 + r];
            float num = cold * Ai * Gp + Gm * Af;
            float c = num * __builtin_amdgcn_rcpf(Af * Ai * Gp);
            cst[hf * 4 + r] = c;
            float Ao = 1.0f + __builtin_amdgcn_exp2f(-go * K1);
            float C2 = __builtin_amdgcn_exp2f(c * K2);
            hout[r] = (C2 - 1.0f) * __builtin_amdgcn_rcpf(Ao * (C2 + 1.0f));
        }
    }
    if (!LAST) {
        bf16x4 plo = { (__bf16)hlo[0], (__bf16)hlo[1], (__bf16)hlo[2], (__bf16)hlo[3] };
        bf16x4 phi = { (__bf16)hhi[0], (__bf16)hhi[1], (__bf16)hhi[2], (__bf16)hhi[3] };
        *(bf16x4*)(Hw + bnl * 80 + 8 * q)      = plo;
        *(bf16x4*)(Hw + bnl * 80 + 32 + 8 * q) = phi;
    }
}

// Grid 8192: hop = bid&1, idx = bid>>1. 4 waves x 1 chain (batch idx*4+w).
// Startup: image loads issue first (no deps), then one dense int4 pidx load
// resolves ALL T-row offsets (items->lp chain hoisted to prep). T0/TR gathers
// prefetched one step ahead; tables are 64 KB -> L1/L2-hot.
__global__ __launch_bounds__(256, 4)
void hop_mfma(const float* __restrict__ user_table,
              const int*   __restrict__ users,
              const int*   __restrict__ pidx,
              const float* __restrict__ wimg,
              const float* __restrict__ T0g,
              const float* __restrict__ TRg,
              float* __restrict__ F0,            // (B,32) sum_p h
              float* __restrict__ F1)
{
    __shared__ __align__(16) char lds[LDS_BYTES];

    const bool second = blockIdx.x & 1;
    const int  idx    = blockIdx.x >> 1;
    const int tid  = threadIdx.x;
    const int lane = tid & 63;
    const int wave = tid >> 6;
    const int q    = lane >> 4;
    const int bnl  = lane & 15;

    // ---- weight image -> LDS: no dependencies, issue first -----------------
    {
        const float4* g4 = (const float4*)((const char*)wimg +
                                           (second ? WIMG_BYTES : 0));
        float4* l4 = (float4*)lds;
        #pragma unroll
        for (int i = 0; i < 5; ++i) l4[i * 256 + tid] = g4[i * 256 + tid];
    }

    // ---- one dense load resolves all row offsets ---------------------------
    const int fb = idx * 4 + wave;
    const int4 ix = *(const int4*)(pidx +
        ((size_t)((second ? BN : 0) + fb) * PP + bnl) * 4);

    bf16x8 bu = loadu8(user_table + (size_t)users[fb] * D + q * 8);

    const char* T0b = (const char*)T0g;
    const char* TRb = (const char*)TRg;

    // step-0 gather (T0[seed], bias included)
    const float* t0p = (const float*)(T0b + ix.x) + 4 * q;
    floatx4 acc0[8];
    #pragma unroll
    for (int mt = 0; mt < 8; ++mt) acc0[mt] = *(const floatx4*)(t0p + 16 * mt);

    const char* Wu  = lds + WU_OFF;
    const char* Whh = lds + WHH_OFF;
    char* Hw = lds + H_OFF + wave * 1280;

    __syncthreads();   // image ready

    float cst[8], hlo[4], hhi[4];

    // ---- step 0: acc0 = T0[seed] ; += Wu @ u -------------------------------
    #pragma unroll
    for (int mt = 0; mt < 8; ++mt) {
        bf16x8 wu = *(const bf16x8*)(Wu + (16 * mt + bnl) * 80 + q * 16);
        acc0[mt] = __builtin_amdgcn_mfma_f32_16x16x32_bf16(wu, bu, acc0[mt], 0, 0, 0);
    }

    // issue step-1 gathers; they land under nonlin0 (~400 cy of cover)
    const float* trp1 = (const float*)(TRb + (ix.y & 0xffff)) + 4 * q;
    const float* tep1 = (const float*)(T0b + (((unsigned)ix.y) >> 16)) + 4 * q;
    floatx4 tr1[8], te1[8];
    #pragma unroll
    for (int mt = 0; mt < 8; ++mt) {
        tr1[mt] = *(const floatx4*)(trp1 + 16 * mt);
        te1[mt] = *(const floatx4*)(tep1 + 16 * mt);
    }

    nonlin<true, false>(acc0, cst, hlo, hhi, Hw, q, bnl);

    // ---- step 1: acc1 = TR[j1] + T0[k1] ; += Whh @ h -----------------------
    floatx4 acc1[8];
    #pragma unroll
    for (int mt = 0; mt < 8; ++mt) acc1[mt] = tr1[mt] + te1[mt];
    {
        bf16x8 bh = *(const bf16x8*)(Hw + bnl * 80 + q * 16);
        #pragma unroll
        for (int mt = 0; mt < 8; ++mt) {
            bf16x8 wh = *(const bf16x8*)(Whh + (16 * mt + bnl) * 80 + q * 16);
            acc1[mt] = __builtin_amdgcn_mfma_f32_16x16x32_bf16(wh, bh, acc1[mt], 0, 0, 0);
        }
    }

    // issue step-2 gathers (hop 1) before nonlin1
    floatx4 tr2[8], te2[8];
    if (second) {
        const float* trp2 = (const float*)(TRb + (ix.z & 0xffff)) + 4 * q;
        const float* tep2 = (const float*)(T0b + (((unsigned)ix.z) >> 16)) + 4 * q;
        #pragma unroll
        for (int mt = 0; mt < 8; ++mt) {
            tr2[mt] = *(const floatx4*)(trp2 + 16 * mt);
            te2[mt] = *(const floatx4*)(tep2 + 16 * mt);
        }
    }

    if (second) nonlin<false, false>(acc1, cst, hlo, hhi, Hw, q, bnl);
    else        nonlin<false, true >(acc1, cst, hlo, hhi, Hw, q, bnl);

    // ---- step 2 (hop 1 only) -----------------------------------------------
    if (second) {
        floatx4 acc2[8];
        #pragma unroll
        for (int mt = 0; mt < 8; ++mt) acc2[mt] = tr2[mt] + te2[mt];
        bf16x8 bh = *(const bf16x8*)(Hw + bnl * 80 + q * 16);
        #pragma unroll
        for (int mt = 0; mt < 8; ++mt) {
            bf16x8 wh = *(const bf16x8*)(Whh + (16 * mt + bnl) * 80 + q * 16);
            acc2[mt] = __builtin_amdgcn_mfma_f32_16x16x32_bf16(wh, bh, acc2[mt], 0, 0, 0);
        }
        nonlin<false, true>(acc2, cst, hlo, hhi, Hw, q, bnl);
    }

    // ---- sum over pairs (reduce across bnl lanes), write F -----------------
    #pragma unroll
    for (int r = 0; r < 4; ++r) {
        #pragma unroll
        for (int m = 1; m < 16; m <<= 1) {
            hlo[r] += __shfl_xor(hlo[r], m);
            hhi[r] += __shfl_xor(hhi[r], m);
        }
    }
    if (bnl == 0) {
        float* Fout = (second ? F1 : F0);
        float4 vlo = { hlo[0], hlo[1], hlo[2], hlo[3] };
        float4 vhi = { hhi[0], hhi[1], hhi[2], hhi[3] };
        *(float4*)(Fout + (size_t)fb * D + 4 * q)      = vlo;
        *(float4*)(Fout + (size_t)fb * D + 16 + 4 * q) = vhi;
    }
}

// Per b: emb0=(ent[items]+F0)@W^T+b ; emb1=(emb0+F1)@W^T+b ; score=dot(u,emb1)
// Loss accumulated via atomicAdd into out[0] (zeroed by prep, stream-ordered).
__global__ __launch_bounds__(256)
void chain_score(const float* __restrict__ user_table,
                 const float* __restrict__ ent_table,
                 const float* __restrict__ agg_w,
                 const float* __restrict__ agg_b,
                 const int*   __restrict__ users,
                 const int*   __restrict__ items,
                 const int*   __restrict__ ratings,
                 const float* __restrict__ F0,
                 const float* __restrict__ F1,
                 float* __restrict__ out)
{
    __shared__ float s[8][33];
    __shared__ float red[8];
    const int tid = threadIdx.x;
    const int bb  = tid >> 5;
    const int j   = tid & 31;
    const int b   = blockIdx.x * 8 + bb;
    const int it  = items[b];

    s[bb][j] = ent_table[(size_t)it * D + j] + F0[(size_t)b * D + j];
    __syncthreads();
    const float* __restrict__ w = agg_w + (size_t)j * D;
    float e0 = agg_b[j];
    #pragma unroll
    for (int k = 0; k < D; ++k) e0 = fmaf(s[bb][k], w[k], e0);
    __syncthreads();
    s[bb][j] = e0 + F1[(size_t)b * D + j];
    __syncthreads();
    float e1 = agg_b[j];
    #pragma unroll
    for (int k = 0; k < D; ++k) e1 = fmaf(s[bb][k], w[k], e1);

    float prod = user_table[(size_t)users[b] * D + j] * e1;
    #pragma unroll
    for (int m = 1; m < 32; m <<= 1) prod += __shfl_xor(prod, m);
    if (j == 0) {
        out[1 + b]      = sigf(prod);
        out[1 + BN + b] = (float)it;
        float r = (float)ratings[b];
        red[bb] = r * logsigf(prod) + (1.0f - r) * logsigf(-prod);
    }
    __syncthreads();
    if (tid == 0) {
        float t = 0.0f;
        #pragma unroll
        for (int qq = 0; qq < 8; ++qq) t += red[qq];
        atomicAdd(out, -t / (float)BN);
    }
}

extern "C" void kernel_launch(void* const* d_in, const int* in_sizes, int n_in,
                              void* d_out, int out_size, void* d_ws, size_t ws_size,
                              hipStream_t stream)
{
    const float* user_table = (const float*)d_in[0];
    const float* ent_table  = (const float*)d_in[1];
    const float* rel_table  = (const float*)d_in[2];
    const float* w_ih0 = (const float*)d_in[3];
    const float* w_hh0 = (const float*)d_in[4];
    const float* b_ih0 = (const float*)d_in[5];
    const float* b_hh0 = (const float*)d_in[6];
    const float* w_ih1 = (const float*)d_in[7];
    const float* w_hh1 = (const float*)d_in[8];
    const float* b_ih1 = (const float*)d_in[9];
    const float* b_hh1 = (const float*)d_in[10];
    const float* agg_w = (const float*)d_in[11];
    const float* agg_b = (const float*)d_in[12];
    const int* users   = (const int*)d_in[13];
    const int* items   = (const int*)d_in[14];
    const int* ratings = (const int*)d_in[15];
    const int* lp0     = (const int*)d_in[16];
    const int* lp1     = (const int*)d_in[17];
    float* out = (float*)d_out;

    float* ws   = (float*)d_ws;
    float* F0   = ws;                              // BN*32
    float* F1   = F0 + (size_t)BN * D;             // BN*32
    float* T0   = F1 + (size_t)BN * D;             // 2*32*128 = 8192
    float* TR   = T0 + 8192;                       // 8192
    float* wimg = TR + 8192;                       // 2*WIMG_BYTES = 10240 f
    int*   pidx = (int*)(wimg + 10240);            // 2*16384*16*4 ints (8 MB)

    prep_tables<<<2177, 256, 0, stream>>>(ent_table, rel_table,
        w_ih0, w_hh0, b_ih0, b_hh0, w_ih1, w_hh1, b_ih1, b_hh1,
        items, lp0, lp1, T0, TR, wimg, pidx, out);
    hop_mfma<<<8192, 256, 0, stream>>>(
        user_table, users, pidx, wimg, T0, TR, F0, F1);
    chain_score<<<BN / 8, 256, 0, stream>>>(
        user_table, ent_table, agg_w, agg_b, users, items, ratings,
        F0, F1, out);
}

// Round 5
// 240.371 us; speedup vs baseline: 1.3243x; 1.3243x over previous
//
#include <hip/hip_runtime.h>
#include <math.h>

#define D  32
#define BN 16384
#define PP 16

typedef __bf16 bf16x8 __attribute__((ext_vector_type(8)));
typedef __bf16 bf16x4 __attribute__((ext_vector_type(4)));
typedef float  floatx4 __attribute__((ext_vector_type(4)));

#define K1 1.44269504088896341f      // log2(e)
#define K2 2.88539008177792681f      // 2*log2(e)

// LDS image (per hop). All tables [128 rows][32 cols] bf16 with ROW STRIDE
// 80 B (40 elems) -> b128 A-fragment reads alias banks only 2-way (free,
// m136); this is the verified R0 addressing. acc-init runs on the MATRIX
// pipe via one-hot B-operands:
//   step 0 : acc = T0t @ onehot(k0)  + Wu @ u        (T0t carries bias)
//   step>=1: acc = TRt @ onehot(j) + T0t @ onehot(k) + Whh @ h
// -> NO scattered loads anywhere in the chain loop.
//   Wu  [128 g][32 d] = Wih[:, 0:32]
//   Whh [128 g][32 d]
//   T0t [128 g][32 k] = bias + Wih[:,32:64] @ ent[k]   (bf16)
//   TRt [128 g][32 j] =        Wih[:, 0:32] @ rel[j]   (bf16, no bias)
#define WU_OFF     0
#define WHH_OFF    10240
#define T0T_OFF    20480
#define TRT_OFF    30720
#define IMG_BYTES  40960
#define H_OFF      40960
#define LDS_BYTES  (IMG_BYTES + 8 * 1280)  // H: 4 waves x 2 chains x 16 x 80B

__device__ __forceinline__ float sigf(float x) {
    float e = __builtin_amdgcn_exp2f(-x * K1);
    return __builtin_amdgcn_rcpf(1.0f + e);
}
__device__ __forceinline__ float logsigf(float x) {
    float ax = fabsf(x);
    float l = log1pf(__expf(-ax));
    return (x >= 0.0f) ? -l : x - l;
}
__device__ __forceinline__ bf16x8 loadu8(const float* __restrict__ p) {
    float4 a = ((const float4*)p)[0], b = ((const float4*)p)[1];
    bf16x8 r = { (__bf16)a.x, (__bf16)a.y, (__bf16)a.z, (__bf16)a.w,
                 (__bf16)b.x, (__bf16)b.y, (__bf16)b.z, (__bf16)b.w };
    return r;
}

// One-hot B-fragment: lane (q,bnl) holds B[k=q*8+j][col=bnl] = (q*8+j==sel).
// bf16(1.0) = 0x3F80. Element j lives in word j>>1, half j&1 (same element
// order the verified bu fragment uses).
__device__ __forceinline__ bf16x8 onehot8(int sel, int q) {
    union { unsigned w[4]; bf16x8 v; } u;
    const unsigned val = 0x3F80u << ((sel & 1) * 16);
    const int grp = sel >> 1;                 // element-pair index 0..15
    #pragma unroll
    for (int wd = 0; wd < 4; ++wd)
        u.w[wd] = (grp == q * 4 + wd) ? val : 0u;
    return u.v;
}

// ---------------------------------------------------------------------------
// ids [0,16384)        : weight images Wu/Whh (bf16, per hop)
// ids [16384,24576)    : T0t (2 hops x 128 g x 32 k, bf16, bias folded in)
// ids [24576,32768)    : TRt (2 hops x 128 g x 32 j, bf16)
// ids [32768,557056)   : pidx (2 hops x 16384 fb x 16 p, 5-bit-packed int)
// id  557056           : zero out[0] (loss accumulator)
__global__ __launch_bounds__(256)
void prep_tables(const float* __restrict__ ent, const float* __restrict__ rel,
                 const float* __restrict__ wih0, const float* __restrict__ whh0,
                 const float* __restrict__ bih0, const float* __restrict__ bhh0,
                 const float* __restrict__ wih1, const float* __restrict__ whh1,
                 const float* __restrict__ bih1, const float* __restrict__ bhh1,
                 const int* __restrict__ items,
                 const int* __restrict__ lp0, const int* __restrict__ lp1,
                 char* __restrict__ imgs, int* __restrict__ pidx,
                 float* __restrict__ out)
{
    const int id = blockIdx.x * 256 + threadIdx.x;
    if (id < 16384) {                            // weight images
        const int hop  = id >> 13;
        const int rest = id & 8191;
        const int mat  = rest >> 12;             // 0 = Wu, 1 = Whh
        const int e    = rest & 4095;
        const int gate = e >> 5, d = e & 31;
        float v = mat ? (hop ? whh1 : whh0)[(size_t)gate * 32 + d]
                      : (hop ? wih1 : wih0)[(size_t)gate * 64 + d];
        __bf16* dst = (__bf16*)(imgs + hop * IMG_BYTES + (mat ? WHH_OFF : WU_OFF));
        dst[gate * 40 + d] = (__bf16)v;
    } else if (id < 24576) {                     // T0t = bias + We@ent
        const int idb = id - 16384;
        const int hop = idb >> 12;
        const int g   = (idb >> 5) & 127;
        const int k   = idb & 31;
        const float* wih = hop ? wih1 : wih0;
        const float4* w4 = (const float4*)(wih + (size_t)g * 64 + 32);
        const float4* e4 = (const float4*)(ent + (size_t)k * 32);
        float a = hop ? bih1[g] + bhh1[g] : bih0[g] + bhh0[g];
        #pragma unroll
        for (int i = 0; i < 8; ++i) {
            float4 w = w4[i], x = e4[i];
            a = fmaf(w.x, x.x, a); a = fmaf(w.y, x.y, a);
            a = fmaf(w.z, x.z, a); a = fmaf(w.w, x.w, a);
        }
        ((__bf16*)(imgs + hop * IMG_BYTES + T0T_OFF))[g * 40 + k] = (__bf16)a;
    } else if (id < 32768) {                     // TRt = Wr@rel (no bias)
        const int idb = id - 24576;
        const int hop = idb >> 12;
        const int g   = (idb >> 5) & 127;
        const int j   = idb & 31;
        const float* wih = hop ? wih1 : wih0;
        const float4* w4 = (const float4*)(wih + (size_t)g * 64);
        const float4* r4 = (const float4*)(rel + (size_t)j * 32);
        float a = 0.0f;
        #pragma unroll
        for (int i = 0; i < 8; ++i) {
            float4 w = w4[i], x = r4[i];
            a = fmaf(w.x, x.x, a); a = fmaf(w.y, x.y, a);
            a = fmaf(w.z, x.z, a); a = fmaf(w.w, x.w, a);
        }
        ((__bf16*)(imgs + hop * IMG_BYTES + TRT_OFF))[g * 40 + j] = (__bf16)a;
    } else if (id < 32768 + 524288) {            // pidx: pack 5 x 5-bit rows
        const int c   = id - 32768;
        const int hop = c >> 18;
        const int rem = c & 262143;
        const int fb  = rem >> 4;
        const int p   = rem & 15;
        const int item = items[fb];
        int w;
        if (hop == 0) {
            const int* il = lp0 + ((size_t)item * PP + p) * 3;
            w = il[0] | (il[1] << 5) | (il[2] << 10);
        } else {
            const int* il = lp1 + ((size_t)item * PP + p) * 5;
            w = il[0] | (il[1] << 5) | (il[2] << 10) | (il[3] << 15)
                      | (il[4] << 20);
        }
        pidx[(size_t)(hop * BN + fb) * PP + p] = w;
    } else if (id == 32768 + 524288) {
        out[0] = 0.0f;                           // loss accumulator
    }
}

// nonlin in C-layout D[gate][pair]: lane (q=lane>>4, p=lane&15), tile mt holds
// gates 16mt+4q+r of pair p. H rows are 80 B (verified R0 stride).
template<bool FIRST, bool LAST>
__device__ __forceinline__ void nonlin(
    floatx4* __restrict__ acc, float* __restrict__ cst,
    float* __restrict__ hlo, float* __restrict__ hhi,
    char* __restrict__ Hw, int q, int bnl)
{
    #pragma unroll
    for (int hf = 0; hf < 2; ++hf) {
        float* hout = hf ? hhi : hlo;
        #pragma unroll
        for (int r = 0; r < 4; ++r) {
            float gi = acc[0 + hf][r], gf = acc[2 + hf][r],
                  gg = acc[4 + hf][r], go = acc[6 + hf][r];
            float Ai = 1.0f + __builtin_amdgcn_exp2f(-gi * K1);
            float Af = 1.0f + __builtin_amdgcn_exp2f(-gf * K1);
            float G2 = __builtin_amdgcn_exp2f(gg * K2);
            float Gp = G2 + 1.0f, Gm = G2 - 1.0f;
            float cold = FIRST ? 0.0f : cst[hf * 4 + r];
            float num = cold * Ai * Gp + Gm * Af;
            float c = num * __builtin_amdgcn_rcpf(Af * Ai * Gp);
            cst[hf * 4 + r] = c;
            float Ao = 1.0f + __builtin_amdgcn_exp2f(-go * K1);
            float C2 = __builtin_amdgcn_exp2f(c * K2);
            hout[r] = (C2 - 1.0f) * __builtin_amdgcn_rcpf(Ao * (C2 + 1.0f));
        }
    }
    if (!LAST) {
        bf16x4 plo = { (__bf16)hlo[0], (__bf16)hlo[1], (__bf16)hlo[2], (__bf16)hlo[3] };
        bf16x4 phi = { (__bf16)hhi[0], (__bf16)hhi[1], (__bf16)hhi[2], (__bf16)hhi[3] };
        *(bf16x4*)(Hw + bnl * 80 + 8 * q)      = plo;
        *(bf16x4*)(Hw + bnl * 80 + 32 + 8 * q) = phi;
    }
}

// Grid 4096: hop = bid&1, idx = bid>>1. 4 waves x 2 chains (batches idx*8+w,
// +4). Per step per chain per tile: 2-3 MFMAs (one-hot table select + weight
// matmul), A-fragments shared across chains. No scattered loads in the loop.
__global__ __launch_bounds__(256, 3)
void hop_mfma(const float* __restrict__ user_table,
              const int*   __restrict__ users,
              const int*   __restrict__ pidx,
              const char*  __restrict__ imgs,
              float* __restrict__ F0,            // (B,32) sum_p h
              float* __restrict__ F1)
{
    __shared__ __align__(16) char lds[LDS_BYTES];

    const bool second = blockIdx.x & 1;
    const int  idx    = blockIdx.x >> 1;
    const int tid  = threadIdx.x;
    const int lane = tid & 63;
    const int wave = tid >> 6;
    const int q    = lane >> 4;
    const int bnl  = lane & 15;

    // ---- per-chain scalars/loads first (overlap with image copy) -----------
    const int fbA = idx * 8 + wave;
    const int fbB = fbA + 4;
    const int ixA = pidx[(size_t)((second ? BN : 0) + fbA) * PP + bnl];
    const int ixB = pidx[(size_t)((second ? BN : 0) + fbB) * PP + bnl];
    bf16x8 buA = loadu8(user_table + (size_t)users[fbA] * D + q * 8);
    bf16x8 buB = loadu8(user_table + (size_t)users[fbB] * D + q * 8);

    // ---- image -> LDS: 2560 float4, exactly 10 per thread ------------------
    {
        const float4* g4 = (const float4*)(imgs + (second ? IMG_BYTES : 0));
        float4* l4 = (float4*)lds;
        #pragma unroll
        for (int i = 0; i < 10; ++i) l4[i * 256 + tid] = g4[i * 256 + tid];
    }
    const char* Wu  = lds + WU_OFF;
    const char* Whh = lds + WHH_OFF;
    const char* T0t = lds + T0T_OFF;
    const char* TRt = lds + TRT_OFF;
    char* HwA = lds + H_OFF + (wave * 2 + 0) * 1280;
    char* HwB = lds + H_OFF + (wave * 2 + 1) * 1280;

    __syncthreads();   // image ready

    float cstA[8], cstB[8], hloA[4], hhiA[4], hloB[4], hhiB[4];
    const floatx4 zf4 = { 0.0f, 0.0f, 0.0f, 0.0f };

    // ---- step 0: acc = T0t@onehot(k0) + Wu@u -------------------------------
    {
        bf16x8 ohA = onehot8(ixA & 31, q);
        bf16x8 ohB = onehot8(ixB & 31, q);
        floatx4 accA[8], accB[8];
        #pragma unroll
        for (int mt = 0; mt < 8; ++mt) {
            const int ro = (16 * mt + bnl) * 80 + q * 16;
            bf16x8 t0f = *(const bf16x8*)(T0t + ro);
            bf16x8 wuf = *(const bf16x8*)(Wu  + ro);
            accA[mt] = __builtin_amdgcn_mfma_f32_16x16x32_bf16(t0f, ohA, zf4, 0, 0, 0);
            accB[mt] = __builtin_amdgcn_mfma_f32_16x16x32_bf16(t0f, ohB, zf4, 0, 0, 0);
            accA[mt] = __builtin_amdgcn_mfma_f32_16x16x32_bf16(wuf, buA, accA[mt], 0, 0, 0);
            accB[mt] = __builtin_amdgcn_mfma_f32_16x16x32_bf16(wuf, buB, accB[mt], 0, 0, 0);
        }
        nonlin<true, false>(accA, cstA, hloA, hhiA, HwA, q, bnl);
        nonlin<true, false>(accB, cstB, hloB, hhiB, HwB, q, bnl);
    }

    // ---- step 1: acc = TRt@onehot(j1) + T0t@onehot(k1) + Whh@h -------------
    {
        bf16x8 ohjA = onehot8((ixA >> 5) & 31, q);
        bf16x8 ohkA = onehot8((ixA >> 10) & 31, q);
        bf16x8 ohjB = onehot8((ixB >> 5) & 31, q);
        bf16x8 ohkB = onehot8((ixB >> 10) & 31, q);
        bf16x8 bhA = *(const bf16x8*)(HwA + bnl * 80 + q * 16);
        bf16x8 bhB = *(const bf16x8*)(HwB + bnl * 80 + q * 16);
        floatx4 accA[8], accB[8];
        #pragma unroll
        for (int mt = 0; mt < 8; ++mt) {
            const int ro = (16 * mt + bnl) * 80 + q * 16;
            bf16x8 trf = *(const bf16x8*)(TRt + ro);
            bf16x8 t0f = *(const bf16x8*)(T0t + ro);
            bf16x8 whf = *(const bf16x8*)(Whh + ro);
            accA[mt] = __builtin_amdgcn_mfma_f32_16x16x32_bf16(trf, ohjA, zf4, 0, 0, 0);
            accB[mt] = __builtin_amdgcn_mfma_f32_16x16x32_bf16(trf, ohjB, zf4, 0, 0, 0);
            accA[mt] = __builtin_amdgcn_mfma_f32_16x16x32_bf16(t0f, ohkA, accA[mt], 0, 0, 0);
            accB[mt] = __builtin_amdgcn_mfma_f32_16x16x32_bf16(t0f, ohkB, accB[mt], 0, 0, 0);
            accA[mt] = __builtin_amdgcn_mfma_f32_16x16x32_bf16(whf, bhA, accA[mt], 0, 0, 0);
            accB[mt] = __builtin_amdgcn_mfma_f32_16x16x32_bf16(whf, bhB, accB[mt], 0, 0, 0);
        }
        if (second) {
            nonlin<false, false>(accA, cstA, hloA, hhiA, HwA, q, bnl);
            nonlin<false, false>(accB, cstB, hloB, hhiB, HwB, q, bnl);
        } else {
            nonlin<false, true>(accA, cstA, hloA, hhiA, HwA, q, bnl);
            nonlin<false, true>(accB, cstB, hloB, hhiB, HwB, q, bnl);
        }
    }

    // ---- step 2 (hop 1 only) -----------------------------------------------
    if (second) {
        bf16x8 ohjA = onehot8((ixA >> 15) & 31, q);
        bf16x8 ohkA = onehot8((ixA >> 20) & 31, q);
        bf16x8 ohjB = onehot8((ixB >> 15) & 31, q);
        bf16x8 ohkB = onehot8((ixB >> 20) & 31, q);
        bf16x8 bhA = *(const bf16x8*)(HwA + bnl * 80 + q * 16);
        bf16x8 bhB = *(const bf16x8*)(HwB + bnl * 80 + q * 16);
        floatx4 accA[8], accB[8];
        #pragma unroll
        for (int mt = 0; mt < 8; ++mt) {
            const int ro = (16 * mt + bnl) * 80 + q * 16;
            bf16x8 trf = *(const bf16x8*)(TRt + ro);
            bf16x8 t0f = *(const bf16x8*)(T0t + ro);
            bf16x8 whf = *(const bf16x8*)(Whh + ro);
            accA[mt] = __builtin_amdgcn_mfma_f32_16x16x32_bf16(trf, ohjA, zf4, 0, 0, 0);
            accB[mt] = __builtin_amdgcn_mfma_f32_16x16x32_bf16(trf, ohjB, zf4, 0, 0, 0);
            accA[mt] = __builtin_amdgcn_mfma_f32_16x16x32_bf16(t0f, ohkA, accA[mt], 0, 0, 0);
            accB[mt] = __builtin_amdgcn_mfma_f32_16x16x32_bf16(t0f, ohkB, accB[mt], 0, 0, 0);
            accA[mt] = __builtin_amdgcn_mfma_f32_16x16x32_bf16(whf, bhA, accA[mt], 0, 0, 0);
            accB[mt] = __builtin_amdgcn_mfma_f32_16x16x32_bf16(whf, bhB, accB[mt], 0, 0, 0);
        }
        nonlin<false, true>(accA, cstA, hloA, hhiA, HwA, q, bnl);
        nonlin<false, true>(accB, cstB, hloB, hhiB, HwB, q, bnl);
    }

    // ---- sum over pairs (reduce across bnl lanes), write F -----------------
    #pragma unroll
    for (int r = 0; r < 4; ++r) {
        #pragma unroll
        for (int m = 1; m < 16; m <<= 1) {
            hloA[r] += __shfl_xor(hloA[r], m);
            hhiA[r] += __shfl_xor(hhiA[r], m);
            hloB[r] += __shfl_xor(hloB[r], m);
            hhiB[r] += __shfl_xor(hhiB[r], m);
        }
    }
    if (bnl == 0) {
        float* Fout = (second ? F1 : F0);
        float4 vloA = { hloA[0], hloA[1], hloA[2], hloA[3] };
        float4 vhiA = { hhiA[0], hhiA[1], hhiA[2], hhiA[3] };
        float4 vloB = { hloB[0], hloB[1], hloB[2], hloB[3] };
        float4 vhiB = { hhiB[0], hhiB[1], hhiB[2], hhiB[3] };
        *(float4*)(Fout + (size_t)fbA * D + 4 * q)      = vloA;
        *(float4*)(Fout + (size_t)fbA * D + 16 + 4 * q) = vhiA;
        *(float4*)(Fout + (size_t)fbB * D + 4 * q)      = vloB;
        *(float4*)(Fout + (size_t)fbB * D + 16 + 4 * q) = vhiB;
    }
}

// Per b: emb0=(ent[items]+F0)@W^T+b ; emb1=(emb0+F1)@W^T+b ; score=dot(u,emb1)
// Loss accumulated via atomicAdd into out[0] (zeroed by prep, stream-ordered).
__global__ __launch_bounds__(256)
void chain_score(const float* __restrict__ user_table,
                 const float* __restrict__ ent_table,
                 const float* __restrict__ agg_w,
                 const float* __restrict__ agg_b,
                 const int*   __restrict__ users,
                 const int*   __restrict__ items,
                 const int*   __restrict__ ratings,
                 const float* __restrict__ F0,
                 const float* __restrict__ F1,
                 float* __restrict__ out)
{
    __shared__ float s[8][33];
    __shared__ float red[8];
    const int tid = threadIdx.x;
    const int bb  = tid >> 5;
    const int j   = tid & 31;
    const int b   = blockIdx.x * 8 + bb;
    const int it  = items[b];

    s[bb][j] = ent_table[(size_t)it * D + j] + F0[(size_t)b * D + j];
    __syncthreads();
    const float* __restrict__ w = agg_w + (size_t)j * D;
    float e0 = agg_b[j];
    #pragma unroll
    for (int k = 0; k < D; ++k) e0 = fmaf(s[bb][k], w[k], e0);
    __syncthreads();
    s[bb][j] = e0 + F1[(size_t)b * D + j];
    __syncthreads();
    float e1 = agg_b[j];
    #pragma unroll
    for (int k = 0; k < D; ++k) e1 = fmaf(s[bb][k], w[k], e1);

    float prod = user_table[(size_t)users[b] * D + j] * e1;
    #pragma unroll
    for (int m = 1; m < 32; m <<= 1) prod += __shfl_xor(prod, m);
    if (j == 0) {
        out[1 + b]      = sigf(prod);
        out[1 + BN + b] = (float)it;
        float r = (float)ratings[b];
        red[bb] = r * logsigf(prod) + (1.0f - r) * logsigf(-prod);
    }
    __syncthreads();
    if (tid == 0) {
        float t = 0.0f;
        #pragma unroll
        for (int qq = 0; qq < 8; ++qq) t += red[qq];
        atomicAdd(out, -t / (float)BN);
    }
}

extern "C" void kernel_launch(void* const* d_in, const int* in_sizes, int n_in,
                              void* d_out, int out_size, void* d_ws, size_t ws_size,
                              hipStream_t stream)
{
    const float* user_table = (const float*)d_in[0];
    const float* ent_table  = (const float*)d_in[1];
    const float* rel_table  = (const float*)d_in[2];
    const float* w_ih0 = (const float*)d_in[3];
    const float* w_hh0 = (const float*)d_in[4];
    const float* b_ih0 = (const float*)d_in[5];
    const float* b_hh0 = (const float*)d_in[6];
    const float* w_ih1 = (const float*)d_in[7];
    const float* w_hh1 = (const float*)d_in[8];
    const float* b_ih1 = (const float*)d_in[9];
    const float* b_hh1 = (const float*)d_in[10];
    const float* agg_w = (const float*)d_in[11];
    const float* agg_b = (const float*)d_in[12];
    const int* users   = (const int*)d_in[13];
    const int* items   = (const int*)d_in[14];
    const int* ratings = (const int*)d_in[15];
    const int* lp0     = (const int*)d_in[16];
    const int* lp1     = (const int*)d_in[17];
    float* out = (float*)d_out;

    float* ws   = (float*)d_ws;
    float* F0   = ws;                              // BN*32 floats
    float* F1   = F0 + (size_t)BN * D;             // BN*32 floats
    char*  imgs = (char*)(F1 + (size_t)BN * D);    // 2 x 40960 B
    int*   pidx = (int*)(imgs + 2 * IMG_BYTES);    // 2*BN*16 ints (2 MB)

    prep_tables<<<2177, 256, 0, stream>>>(ent_table, rel_table,
        w_ih0, w_hh0, b_ih0, b_hh0, w_ih1, w_hh1, b_ih1, b_hh1,
        items, lp0, lp1, imgs, pidx, out);
    hop_mfma<<<4096, 256, 0, stream>>>(
        user_table, users, pidx, imgs, F0, F1);
    chain_score<<<BN / 8, 256, 0, stream>>>(
        user_table, ent_table, agg_w, agg_b, users, items, ratings,
        F0, F1, out);
}